// Round 9
// baseline (360.388 us; speedup 1.0000x reference)
//
#include <hip/hip_runtime.h>
#include <hip/hip_bf16.h>
#include <stdint.h>

// Gram matrix: G = X @ X^T, X = [512, 65536] fp32, out = [512, 512] fp32.
// Round 9: K2 GEMM rebuilt BARRIER-FREE and LDS-FREE.
// r5-r8 evidence: every variant of LDS staging (2-barrier, XCD-affine, raw
// vmcnt pipeline) lands at the same ~58 us — the global->LDS->reg round trip
// stays on the critical path (compiler inserts conservative vmcnt before
// ds_read aliasing global_load_lds). Fix: fragments are loaded DIRECTLY
// global->VGPR. An MFMA A-frag load (16 rows x 32 cols, 16 B/lane) touches
// 16 fully-consumed 64 B lines — the same line count as a lane-linear
// dwordx4, so it costs the same BW. The bf16 ws (67 MB) is LLC-resident.
//   - wave = one 64x64 output tile, K-chunk 1024; depth-1 reg pipeline;
//     NO barriers in the K-loop.
//   - tiles at 64-grain: 8 diag (A=B -> half loads) + 28 upper; grid =
//     36 tiles x 16 K-chunks = 576 blocks (all co-resident at 3 blk/CU).
//   - epilogue: 4-wave LDS reduce (16 KB) then ONE coalesced global
//     atomicAdd pass: 2.36M atomics (was 8.4M; r6 priced them ~2us/M).
//   - mirror now 64-granular (gemm writes upper at 64-grain).
// K1 cvt unchanged (~50 us, near the read-X-once HBM floor).
// Fallback if ws_size < 64 MiB: r1's fused kernel (known-good 135 us).

typedef short bf16x8 __attribute__((ext_vector_type(8)));   // 8 bf16 = 4 VGPRs
typedef float f32x4  __attribute__((ext_vector_type(4)));   // MFMA acc

#define HW    65536
#define CDIM  512

__device__ __forceinline__ short f2bf(float f) {
    __hip_bfloat16 h = __float2bfloat16(f);   // RNE
    short s;
    __builtin_memcpy(&s, &h, sizeof(short));
    return s;
}

__device__ __forceinline__ bf16x8 cvt8(float4 a, float4 b) {
    bf16x8 v;
    v[0] = f2bf(a.x); v[1] = f2bf(a.y); v[2] = f2bf(a.z); v[3] = f2bf(a.w);
    v[4] = f2bf(b.x); v[5] = f2bf(b.y); v[6] = f2bf(b.z); v[7] = f2bf(b.w);
    return v;
}

// ---------------- K1: fp32 -> bf16 convert ----------------
__global__ __launch_bounds__(256)
void cvt_kernel(const float* __restrict__ X, unsigned short* __restrict__ Xb) {
    const size_t i = ((size_t)blockIdx.x * 256 + threadIdx.x) * 8;
    float4 a = *(const float4*)(X + i);
    float4 b = *(const float4*)(X + i + 4);
    bf16x8 v = cvt8(a, b);
    *(bf16x8*)(Xb + i) = v;
}

// ---------------- K2: symmetric bf16 GEMM, barrier-free ----------------
__global__ __launch_bounds__(256, 3)
void gram_bf16_kernel(const unsigned short* __restrict__ Xb,
                      float* __restrict__ out) {
    // p -> (tile, sk): tile = p % 36 (8 diag + 28 upper), sk = p / 36 (0..15)
    const int p    = blockIdx.x;
    const int tile = p % 36;
    const int sk   = p / 36;
    const int TI[36] = {0,1,2,3,4,5,6,7,
                        0,0,0,0,0,0,0, 1,1,1,1,1,1, 2,2,2,2,2,
                        3,3,3,3, 4,4,4, 5,5, 6};
    const int TJ[36] = {0,1,2,3,4,5,6,7,
                        1,2,3,4,5,6,7, 2,3,4,5,6,7, 3,4,5,6,7,
                        4,5,6,7, 5,6,7, 6,7, 7};
    const int ti = TI[tile], tj = TJ[tile];
    const bool diag = (ti == tj);

    const int wave = threadIdx.x >> 6;
    const int lane = threadIdx.x & 63;
    const int fm   = lane & 15;           // frag row within 16 (m), and C col
    const int kg   = lane >> 4;           // k-group: 8 contiguous k each
    const int k0   = sk * 4096 + wave * 1024;   // this wave's K range

    // per-lane fragment stream pointers (frag i = rows 16i..16i+15)
    const unsigned short* pa[4];
    const unsigned short* pb[4];
#pragma unroll
    for (int i = 0; i < 4; ++i) {
        pa[i] = Xb + (size_t)(ti * 64 + i * 16 + fm) * HW + k0 + kg * 8;
        pb[i] = Xb + (size_t)(tj * 64 + i * 16 + fm) * HW + k0 + kg * 8;
    }

    f32x4 acc[4][4];
#pragma unroll
    for (int i = 0; i < 4; ++i)
#pragma unroll
        for (int j = 0; j < 4; ++j)
            acc[i][j] = (f32x4){0.f, 0.f, 0.f, 0.f};

#define MFMA_SET(A_, B_)                                                   \
    do {                                                                   \
        _Pragma("unroll")                                                  \
        for (int i = 0; i < 4; ++i)                                        \
            _Pragma("unroll")                                              \
            for (int j = 0; j < 4; ++j)                                    \
                acc[i][j] = __builtin_amdgcn_mfma_f32_16x16x32_bf16(       \
                    (A_)[i], (B_)[j], acc[i][j], 0, 0, 0);                 \
    } while (0)

    if (diag) {
        // A = B: 4 loads per K-32, acc[i][j] += A[i] x A[j]
        bf16x8 A0[4], A1[4];
#pragma unroll
        for (int i = 0; i < 4; ++i) A0[i] = *(const bf16x8*)(pa[i]);
        for (int kk = 0; kk < 1024; kk += 64) {
#pragma unroll
            for (int i = 0; i < 4; ++i)
                A1[i] = *(const bf16x8*)(pa[i] + kk + 32);
            MFMA_SET(A0, A0);
            const int kn = (kk + 64 < 1024) ? kk + 64 : 0;   // tail: dummy
#pragma unroll
            for (int i = 0; i < 4; ++i)
                A0[i] = *(const bf16x8*)(pa[i] + kn);
            MFMA_SET(A1, A1);
        }
    } else {
        bf16x8 A0[4], B0[4], A1[4], B1[4];
#pragma unroll
        for (int i = 0; i < 4; ++i) {
            A0[i] = *(const bf16x8*)(pa[i]);
            B0[i] = *(const bf16x8*)(pb[i]);
        }
        for (int kk = 0; kk < 1024; kk += 64) {
#pragma unroll
            for (int i = 0; i < 4; ++i) {
                A1[i] = *(const bf16x8*)(pa[i] + kk + 32);
                B1[i] = *(const bf16x8*)(pb[i] + kk + 32);
            }
            MFMA_SET(A0, B0);
            const int kn = (kk + 64 < 1024) ? kk + 64 : 0;   // tail: dummy
#pragma unroll
            for (int i = 0; i < 4; ++i) {
                A0[i] = *(const bf16x8*)(pa[i] + kn);
                B0[i] = *(const bf16x8*)(pb[i] + kn);
            }
            MFMA_SET(A1, B1);
        }
    }
#undef MFMA_SET

    // ---- epilogue: reduce the block's 4 K-chunks in LDS, then one
    //      coalesced global atomicAdd pass ----
    __shared__ float red[4096];        // 64x64 tile, 16 KB
    for (int e = threadIdx.x; e < 4096; e += 256) red[e] = 0.f;
    __syncthreads();

    // C/D layout (verified m89/m91): col = lane&15, row = (lane>>4)*4 + reg
#pragma unroll
    for (int i = 0; i < 4; ++i)
#pragma unroll
        for (int j = 0; j < 4; ++j)
#pragma unroll
            for (int r = 0; r < 4; ++r) {
                const int row = i * 16 + kg * 4 + r;
                const int col = j * 16 + fm;
                atomicAdd(&red[row * 64 + col], acc[i][j][r]);
            }
    __syncthreads();

    const int R0 = ti * 64, C0 = tj * 64;
    for (int e = threadIdx.x; e < 4096; e += 256) {
        const int r = e >> 6, c = e & 63;
        atomicAdd(out + (size_t)(R0 + r) * CDIM + C0 + c, red[e]);
    }
}

// ---------------- K3: mirror upper -> lower (64-granular) ----------------
__global__ __launch_bounds__(256)
void mirror_kernel(float* __restrict__ out) {
    const int id = blockIdx.x * 256 + threadIdx.x;   // 0..262143
    const int r = id >> 9;
    const int c = id & 511;
    if ((r >> 6) > (c >> 6))
        out[id] = out[c * CDIM + r];
}

// ---------------- fallback: r1 fused kernel (known-good 135 us) ----------------
#define FKC   2048
#define FBK   32
#define FLDSS 40

__global__ __launch_bounds__(256, 2)
void gram_fallback(const float* __restrict__ X, float* __restrict__ out) {
    const int tile  = blockIdx.x;
    const int ti    = tile >> 2;
    const int tj    = tile & 3;
    const int chunk = blockIdx.y;

    __shared__ short As[128 * FLDSS];
    __shared__ short Bs[128 * FLDSS];

    const int t    = threadIdx.x;
    const int wave = t >> 6;
    const int lane = t & 63;
    const int wm   = wave & 1;
    const int wn   = wave >> 1;

    const int srow  = t >> 1;
    const int shalf = (t & 1) * 16;
    const float* pa = X + (size_t)(ti * 128 + srow) * HW + chunk * FKC + shalf;
    const float* pb = X + (size_t)(tj * 128 + srow) * HW + chunk * FKC + shalf;
    short* wa = As + srow * FLDSS + shalf;
    short* wb = Bs + srow * FLDSS + shalf;

    const int fm = lane & 15;
    const int kg = lane >> 4;
    int a_off[4], b_off[4];
#pragma unroll
    for (int i = 0; i < 4; ++i) {
        a_off[i] = (wm * 64 + i * 16 + fm) * FLDSS + kg * 8;
        b_off[i] = (wn * 64 + i * 16 + fm) * FLDSS + kg * 8;
    }

    f32x4 acc[4][4];
#pragma unroll
    for (int i = 0; i < 4; ++i)
#pragma unroll
        for (int j = 0; j < 4; ++j)
            acc[i][j] = (f32x4){0.f, 0.f, 0.f, 0.f};

    for (int it = 0; it < FKC / FBK; ++it) {
        float4 a0 = *(const float4*)(pa + 0);
        float4 a1 = *(const float4*)(pa + 4);
        float4 a2 = *(const float4*)(pa + 8);
        float4 a3 = *(const float4*)(pa + 12);
        float4 b0 = *(const float4*)(pb + 0);
        float4 b1 = *(const float4*)(pb + 4);
        float4 b2 = *(const float4*)(pb + 8);
        float4 b3 = *(const float4*)(pb + 12);

        bf16x8 va0 = cvt8(a0, a1), va1 = cvt8(a2, a3);
        bf16x8 vb0 = cvt8(b0, b1), vb1 = cvt8(b2, b3);

        __syncthreads();
        *(bf16x8*)(wa + 0) = va0;
        *(bf16x8*)(wa + 8) = va1;
        *(bf16x8*)(wb + 0) = vb0;
        *(bf16x8*)(wb + 8) = vb1;
        __syncthreads();

        bf16x8 af[4], bfr[4];
#pragma unroll
        for (int i = 0; i < 4; ++i) af[i]  = *(const bf16x8*)(As + a_off[i]);
#pragma unroll
        for (int j = 0; j < 4; ++j) bfr[j] = *(const bf16x8*)(Bs + b_off[j]);

#pragma unroll
        for (int i = 0; i < 4; ++i)
#pragma unroll
            for (int j = 0; j < 4; ++j)
                acc[i][j] = __builtin_amdgcn_mfma_f32_16x16x32_bf16(
                    af[i], bfr[j], acc[i][j], 0, 0, 0);

        pa += FBK;
        pb += FBK;
    }

    const int orow0 = ti * 128 + wm * 64 + (lane >> 4) * 4;
    const int ocol0 = tj * 128 + wn * 64 + fm;
#pragma unroll
    for (int i = 0; i < 4; ++i)
#pragma unroll
        for (int j = 0; j < 4; ++j)
#pragma unroll
            for (int r = 0; r < 4; ++r)
                atomicAdd(out + (orow0 + i * 16 + r) * CDIM + ocol0 + j * 16,
                          acc[i][j][r]);
}

extern "C" void kernel_launch(void* const* d_in, const int* in_sizes, int n_in,
                              void* d_out, int out_size, void* d_ws, size_t ws_size,
                              hipStream_t stream) {
    const float* x = (const float*)d_in[0];
    float* out = (float*)d_out;
    const size_t need = (size_t)CDIM * HW * 2;   // 67,108,864 B bf16 copy

    hipMemsetAsync(d_out, 0, (size_t)out_size * sizeof(float), stream);

    if (ws_size >= need) {
        unsigned short* xb = (unsigned short*)d_ws;
        cvt_kernel<<<dim3(16384), dim3(256), 0, stream>>>(x, xb);
        gram_bf16_kernel<<<dim3(576), dim3(256), 0, stream>>>(xb, out);
        mirror_kernel<<<dim3(1024), dim3(256), 0, stream>>>(out);
    } else {
        gram_fallback<<<dim3(16, 32), dim3(256), 0, stream>>>(x, out);
    }
}

// Round 10
// 238.696 us; speedup vs baseline: 1.5098x; 1.5098x over previous
//
#include <hip/hip_runtime.h>
#include <hip/hip_bf16.h>

// Gram matrix: G = X @ X^T, X = [512, 65536] fp32, out = [512, 512] fp32.
// Round 10: r1's fused kernel (the best memory-delivery structure measured:
// 7.9 TB/s logical, 135 us for 1.07 GB) + SYMMETRY. K-loop untouched from r1.
//   - tiles at 128-grain: 4 diag (stage ONE panel, use as A and B) +
//     6 upper off-diag (stage two panels). Logical reads 1.07 GB -> 537 MB.
//   - grid 512 = 2 blocks/CU (r1's proven occupancy), balanced staging:
//     diag = 4 tiles x 32 chunks (KC=2048, 64 iters x 1 panel),
//     upper = 6 tiles x 64 chunks (KC=1024, 32 iters x 2 panels);
//     every block stages 512 KB fp32. Diag (2x MFMA work) launched first.
//   - epilogue: r1's row-major coalesced atomics, 8.4M total (the floor
//     for this grid; r6 showed doubling them costs ~17 us).
//   - mirror kernel copies upper tiles transposed into lower (1 MB).
// No workspace needed (r5-r8's cvt+bf16 split totals ~106 us of kernels;
// this path targets ~80-90 with one fewer pass over memory).
// History: r9's LDS-free direct-fragment gemm = 170 us latency-bound even
// LLC-warm — scheduling restructures keep losing to r1's plain 2-barrier
// loop; this round changes only the ARITHMETIC (fewer logical bytes).

typedef short bf16x8 __attribute__((ext_vector_type(8)));   // 8 bf16 = 4 VGPRs
typedef float f32x4  __attribute__((ext_vector_type(4)));   // MFMA acc

#define HW    65536
#define CDIM  512
#define BK    32
#define LDSS  40        // r1's stride (conflict counter proved stride-insensitive)

__device__ __forceinline__ short f2bf(float f) {
    __hip_bfloat16 h = __float2bfloat16(f);   // RNE
    short s;
    __builtin_memcpy(&s, &h, sizeof(short));
    return s;
}

__device__ __forceinline__ bf16x8 cvt8(float4 a, float4 b) {
    bf16x8 v;
    v[0] = f2bf(a.x); v[1] = f2bf(a.y); v[2] = f2bf(a.z); v[3] = f2bf(a.w);
    v[4] = f2bf(b.x); v[5] = f2bf(b.y); v[6] = f2bf(b.z); v[7] = f2bf(b.w);
    return v;
}

__global__ __launch_bounds__(256, 2)
void gram_kernel(const float* __restrict__ X, float* __restrict__ out) {
    // decode: p<128  -> diag tile ti=tj=p>>5, chunk=p&31, KC=2048 (64 iters)
    //         p>=128 -> upper tile o=(p-128)>>6, chunk=(p-128)&63, KC=1024
    const int p = blockIdx.x;
    int ti, tj, kbase, iters;
    if (p < 128) {
        ti = tj = p >> 5;
        kbase = (p & 31) * 2048;
        iters = 64;
    } else {
        const int q = p - 128;
        const int o = q >> 6;
        const int TI[6] = {0, 0, 0, 1, 1, 2};
        const int TJ[6] = {1, 2, 3, 2, 3, 3};
        ti = TI[o]; tj = TJ[o];
        kbase = (q & 63) * 1024;
        iters = 32;
    }
    const bool diag = (ti == tj);

    __shared__ short As[128 * LDSS];
    __shared__ short Bs[128 * LDSS];

    const int t    = threadIdx.x;
    const int wave = t >> 6;
    const int lane = t & 63;
    const int wm   = wave & 1;          // 2x2 wave grid, each wave = 64x64
    const int wn   = wave >> 1;

    // --- staging mapping (r1's): 2 threads per row, 16 consecutive fp32 ---
    const int srow  = t >> 1;           // 0..127
    const int shalf = (t & 1) * 16;     // k offset 0 or 16
    const float* pa = X + (size_t)(ti * 128 + srow) * HW + kbase + shalf;
    const float* pb = X + (size_t)(tj * 128 + srow) * HW + kbase + shalf;
    short* wa = As + srow * LDSS + shalf;
    short* wb = Bs + srow * LDSS + shalf;

    // --- fragment read offsets (A-operand: m = lane&15, k-group = lane>>4) ---
    const int fm = lane & 15;
    const int kg = lane >> 4;           // 0..3, each group = 8 contiguous k
    int a_off[4], b_off[4];
#pragma unroll
    for (int i = 0; i < 4; ++i) {
        a_off[i] = (wm * 64 + i * 16 + fm) * LDSS + kg * 8;
        b_off[i] = (wn * 64 + i * 16 + fm) * LDSS + kg * 8;
    }
    const short* Bbase = diag ? As : Bs;   // diag: B frags read the A panel

    f32x4 acc[4][4];
#pragma unroll
    for (int i = 0; i < 4; ++i)
#pragma unroll
        for (int j = 0; j < 4; ++j)
            acc[i][j] = (f32x4){0.f, 0.f, 0.f, 0.f};

    for (int it = 0; it < iters; ++it) {
        // global fp32 loads (16 floats per panel row-half; diag: A only)
        float4 a0 = *(const float4*)(pa + 0);
        float4 a1 = *(const float4*)(pa + 4);
        float4 a2 = *(const float4*)(pa + 8);
        float4 a3 = *(const float4*)(pa + 12);
        float4 b0, b1, b2, b3;
        if (!diag) {
            b0 = *(const float4*)(pb + 0);
            b1 = *(const float4*)(pb + 4);
            b2 = *(const float4*)(pb + 8);
            b3 = *(const float4*)(pb + 12);
        }

        bf16x8 va0 = cvt8(a0, a1), va1 = cvt8(a2, a3);
        bf16x8 vb0, vb1;
        if (!diag) { vb0 = cvt8(b0, b1); vb1 = cvt8(b2, b3); }

        __syncthreads();   // prior iteration's LDS reads complete
        *(bf16x8*)(wa + 0) = va0;
        *(bf16x8*)(wa + 8) = va1;
        if (!diag) {
            *(bf16x8*)(wb + 0) = vb0;
            *(bf16x8*)(wb + 8) = vb1;
        }
        __syncthreads();   // stage visible to all waves

        bf16x8 af[4], bfr[4];
#pragma unroll
        for (int i = 0; i < 4; ++i) af[i]  = *(const bf16x8*)(As + a_off[i]);
#pragma unroll
        for (int j = 0; j < 4; ++j) bfr[j] = *(const bf16x8*)(Bbase + b_off[j]);

#pragma unroll
        for (int i = 0; i < 4; ++i)
#pragma unroll
            for (int j = 0; j < 4; ++j)
                acc[i][j] = __builtin_amdgcn_mfma_f32_16x16x32_bf16(
                    af[i], bfr[j], acc[i][j], 0, 0, 0);

        pa += BK;
        pb += BK;
    }

    // --- epilogue: row-major coalesced atomics (diag/upper tiles only) ---
    // C/D layout (verified m89/m91): col = lane&15, row = (lane>>4)*4 + reg
    const int orow0 = ti * 128 + wm * 64 + (lane >> 4) * 4;
    const int ocol0 = tj * 128 + wn * 64 + fm;
#pragma unroll
    for (int i = 0; i < 4; ++i)
#pragma unroll
        for (int j = 0; j < 4; ++j)
#pragma unroll
            for (int r = 0; r < 4; ++r)
                atomicAdd(out + (orow0 + i * 16 + r) * CDIM + ocol0 + j * 16,
                          acc[i][j][r]);
}

// ---------------- mirror: copy upper tiles transposed into lower ----------------
__global__ __launch_bounds__(256)
void mirror_kernel(float* __restrict__ out) {
    const int id = blockIdx.x * 256 + threadIdx.x;   // 0..262143
    const int r = id >> 9;
    const int c = id & 511;
    if ((r >> 7) > (c >> 7))
        out[id] = out[c * CDIM + r];
}

extern "C" void kernel_launch(void* const* d_in, const int* in_sizes, int n_in,
                              void* d_out, int out_size, void* d_ws, size_t ws_size,
                              hipStream_t stream) {
    const float* x = (const float*)d_in[0];
    float* out = (float*)d_out;

    // zero the accumulator (harness poisons d_out with 0xAA before every launch)
    hipMemsetAsync(d_out, 0, (size_t)out_size * sizeof(float), stream);

    gram_kernel<<<dim3(512), dim3(256), 0, stream>>>(x, out);
    mirror_kernel<<<dim3(1024), dim3(256), 0, stream>>>(out);
}